// Round 1
// baseline (5329.519 us; speedup 1.0000x reference)
//
#include <hip/hip_runtime.h>
#include <math.h>

#define NODES 1024
#define HIDF  64
#define BT    384                  // B*T
#define NTOK  (BT*NODES)           // 393216
#define LN_EPS 1e-5f

__device__ __forceinline__ float gelu_exact(float x){
    return 0.5f * x * (1.0f + erff(x * 0.70710678118654752f));
}
__device__ __forceinline__ float sigmoidf_(float x){
    return 1.0f / (1.0f + __expf(-x));
}

// ---------------------------------------------------------------------------
// a_adp = softmax(relu(emb_src @ emb_dst^T), axis=-1)   [1024 x 1024]
// one block per row
// ---------------------------------------------------------------------------
__global__ __launch_bounds__(256) void k_adp(const float* __restrict__ es,
                                             const float* __restrict__ ed,
                                             float* __restrict__ aadp){
    __shared__ float srow[1024];
    __shared__ float s_es[16];
    __shared__ float sredm[4];
    __shared__ float sreds[4];
    const int n   = blockIdx.x;
    const int tid = threadIdx.x;
    const int wid = tid >> 6, lane = tid & 63;
    if (tid < 16) s_es[tid] = es[n*16 + tid];
    __syncthreads();
    float lmax = 0.0f;
    for (int m = tid; m < 1024; m += 256){
        const float* edm = ed + m*16;
        float z = 0.f;
        #pragma unroll
        for (int r = 0; r < 16; r++) z = fmaf(s_es[r], edm[r], z);
        z = fmaxf(z, 0.0f);            // relu
        srow[m] = z;
        lmax = fmaxf(lmax, z);
    }
    #pragma unroll
    for (int o = 32; o > 0; o >>= 1) lmax = fmaxf(lmax, __shfl_xor(lmax, o, 64));
    if (lane == 0) sredm[wid] = lmax;
    __syncthreads();
    const float tmax = fmaxf(fmaxf(sredm[0], sredm[1]), fmaxf(sredm[2], sredm[3]));
    float lsum = 0.f;
    for (int m = tid; m < 1024; m += 256){
        float e = expf(srow[m] - tmax);
        srow[m] = e;
        lsum += e;
    }
    #pragma unroll
    for (int o = 32; o > 0; o >>= 1) lsum += __shfl_xor(lsum, o, 64);
    if (lane == 0) sreds[wid] = lsum;
    __syncthreads();
    const float inv = 1.0f / (sreds[0] + sreds[1] + sreds[2] + sreds[3]);
    for (int m = tid; m < 1024; m += 256) aadp[(size_t)n*1024 + m] = srow[m] * inv;
}

// ---------------------------------------------------------------------------
// a_bwdT[n][m] = a_fwd[m][n]
// ---------------------------------------------------------------------------
__global__ __launch_bounds__(256) void k_transpose(const float* __restrict__ a,
                                                   float* __restrict__ at){
    __shared__ float t[32][33];
    const int bx = blockIdx.x * 32, by = blockIdx.y * 32;
    const int tx = threadIdx.x & 31, ty = threadIdx.x >> 5;   // ty 0..7
    #pragma unroll
    for (int i = 0; i < 4; i++)
        t[ty + 8*i][tx] = a[(size_t)(by + ty + 8*i)*1024 + bx + tx];
    __syncthreads();
    #pragma unroll
    for (int i = 0; i < 4; i++)
        at[(size_t)(bx + ty + 8*i)*1024 + by + tx] = t[tx][ty + 8*i];
}

// ---------------------------------------------------------------------------
// Gating kernel: per token computes
//   gates[4], scale[64], src_gate, dst_gate, and acc = g0*(x@W_self^T + b_self)
// One wave handles 4 tokens; block = 4 waves = 16 tokens/pass, 4 passes.
// ---------------------------------------------------------------------------
__global__ __launch_bounds__(256, 2) void k_gating(
    const float* __restrict__ x,    const float* __restrict__ ctx,
    const float* __restrict__ Wg1,  const float* __restrict__ bg1,
    const float* __restrict__ Wg2,  const float* __restrict__ bg2,
    const float* __restrict__ Ws1,  const float* __restrict__ bs1,
    const float* __restrict__ Ws2,  const float* __restrict__ bs2,
    const float* __restrict__ Wsrc, const float* __restrict__ bsrc,
    const float* __restrict__ Wdst, const float* __restrict__ bdst,
    const float* __restrict__ Wself,const float* __restrict__ bself,
    float* __restrict__ gates, float* __restrict__ scale,
    float* __restrict__ srcg,  float* __restrict__ dstg,
    float* __restrict__ acc)
{
    __shared__ float sWg1[64*65];
    __shared__ float sWs1[64*65];
    __shared__ float sWs2[64*65];
    __shared__ float sWself[64*65];
    __shared__ float sWg2[4*64];
    __shared__ float sTok[16][64];   // ctx, later reused for x
    __shared__ float sHg[16][64];
    __shared__ float sHs[16][64];
    __shared__ float sG[16];

    const int tid = threadIdx.x;
    for (int idx = tid; idx < 4096; idx += 256){
        const int o = idx >> 6, k = idx & 63;
        sWg1[o*65+k]   = Wg1[idx];
        sWs1[o*65+k]   = Ws1[idx];
        sWs2[o*65+k]   = Ws2[idx];
        sWself[o*65+k] = Wself[idx];
    }
    sWg2[tid] = Wg2[tid];
    __syncthreads();

    const int w = tid >> 6, lane = tid & 63;
    const float bg1v = bg1[lane], bs1v = bs1[lane], bs2v = bs2[lane], bselfv = bself[lane];
    const float wsrcv = Wsrc[lane], wdstv = Wdst[lane];
    const float bsrcv = bsrc[0],  bdstv = bdst[0];

    for (int pass = 0; pass < 4; pass++){
        const int tokbase = blockIdx.x*64 + pass*16 + w*4;   // 4 tokens of this wave
        // stage ctx
        #pragma unroll
        for (int t = 0; t < 4; t++)
            sTok[w*4+t][lane] = ctx[(size_t)(tokbase+t)*64 + lane];
        __syncthreads();
        // hidden_g / hidden_s
        float hg[4] = {bg1v, bg1v, bg1v, bg1v};
        float hs[4] = {bs1v, bs1v, bs1v, bs1v};
        for (int k = 0; k < 64; k++){
            const float wg = sWg1[lane*65+k];
            const float wsv = sWs1[lane*65+k];
            #pragma unroll
            for (int t = 0; t < 4; t++){
                const float c = sTok[w*4+t][k];
                hg[t] = fmaf(c, wg,  hg[t]);
                hs[t] = fmaf(c, wsv, hs[t]);
            }
        }
        #pragma unroll
        for (int t = 0; t < 4; t++){
            sHg[w*4+t][lane] = gelu_exact(hg[t]);
            sHs[w*4+t][lane] = gelu_exact(hs[t]);
        }
        // src/dst gates (wave reduce over ctx)
        #pragma unroll
        for (int t = 0; t < 4; t++){
            const float c = sTok[w*4+t][lane];
            float ps = c * wsrcv, pd = c * wdstv;
            #pragma unroll
            for (int o = 32; o > 0; o >>= 1){
                ps += __shfl_xor(ps, o, 64);
                pd += __shfl_xor(pd, o, 64);
            }
            if (lane == 0){
                srcg[tokbase+t] = sigmoidf_(ps + bsrcv);
                dstg[tokbase+t] = sigmoidf_(pd + bdstv);
            }
        }
        __syncthreads();
        // scale = sigmoid(hidden_s @ Ws2^T + bs2)
        {
            float sc[4] = {bs2v, bs2v, bs2v, bs2v};
            for (int k = 0; k < 64; k++){
                const float wv = sWs2[lane*65+k];
                #pragma unroll
                for (int t = 0; t < 4; t++) sc[t] = fmaf(sHs[w*4+t][k], wv, sc[t]);
            }
            #pragma unroll
            for (int t = 0; t < 4; t++)
                scale[(size_t)(tokbase+t)*64 + lane] = sigmoidf_(sc[t]);
        }
        // gates = sigmoid(hidden_g @ Wg2^T + bg2)  (lanes 0..15: t=lane>>2, j=lane&3)
        if (lane < 16){
            const int t = lane >> 2, j = lane & 3;
            float g = bg2[j];
            for (int k = 0; k < 64; k++) g = fmaf(sHg[w*4+t][k], sWg2[j*64+k], g);
            g = sigmoidf_(g);
            gates[(size_t)(tokbase+t)*4 + j] = g;
            if (j == 0) sG[w*4+t] = g;
        }
        // stage x (reuse sTok)
        #pragma unroll
        for (int t = 0; t < 4; t++)
            sTok[w*4+t][lane] = x[(size_t)(tokbase+t)*64 + lane];
        __syncthreads();
        // acc = g0 * (x @ W_self^T + b_self)
        float sv[4] = {bselfv, bselfv, bselfv, bselfv};
        for (int k = 0; k < 64; k++){
            const float wv = sWself[lane*65+k];
            #pragma unroll
            for (int t = 0; t < 4; t++) sv[t] = fmaf(sTok[w*4+t][k], wv, sv[t]);
        }
        #pragma unroll
        for (int t = 0; t < 4; t++)
            acc[(size_t)(tokbase+t)*64 + lane] = sG[w*4+t] * sv[t];
        __syncthreads();
    }
}

// ---------------------------------------------------------------------------
// Diffusion GEMM + fused linear/gate epilogue.
//   next[bt, n0:n0+64, :] = adj[n0:n0+64, :] @ (src[bt] * mgate[bt])   (K=1024)
//   if WRITE_TMP: tmp = next
//   acc[bt,n,o] += gates[bt,n][branch] * (sum_f next[n,f]*W[o,f] + bias[o])
// block: 256 threads, 64x64 tile, 4x4 per-thread register tile.
// ---------------------------------------------------------------------------
template<bool HAS_MGATE, bool WRITE_TMP>
__global__ __launch_bounds__(256) void k_diff(
    const float* __restrict__ adj, const float* __restrict__ src,
    const float* __restrict__ mgate, const float* __restrict__ W,
    const float* __restrict__ bias, const float* __restrict__ gates,
    const int branch, float* __restrict__ acc, float* __restrict__ tmpout)
{
    __shared__ float sAT[64*68];   // A transposed: sAT[kk][nn]
    __shared__ float sB [64*68];   // sB[kk][f]
    __shared__ float sWT[64*68];   // W transposed: sWT[f][o]

    const int tid = threadIdx.x;
    const int nt  = blockIdx.x;          // node tile 0..15
    const int bt  = blockIdx.y;          // 0..383
    const int n0  = nt * 64;
    const int row  = tid >> 4;           // 0..15
    const int col4 = (tid & 15) * 4;     // 0,4,...,60

    // stage W^T once (read in epilogue only)
    for (int idx = tid; idx < 4096; idx += 256){
        const int o = idx >> 6, f = idx & 63;
        sWT[f*68 + o] = W[idx];
    }

    float accr[4][4] = {{0.f}};
    const float* srcbt = src + (size_t)bt * (1024*64);
    const float* mg    = HAS_MGATE ? (mgate + (size_t)bt * 1024) : nullptr;

    for (int m0 = 0; m0 < 1024; m0 += 64){
        // A tile: adj[(n0+nn)][m0+kk] -> sAT[kk][nn]
        #pragma unroll
        for (int i = 0; i < 4; i++){
            const int nn = row + 16*i;
            const float4 av = *(const float4*)&adj[(size_t)(n0+nn)*1024 + m0 + col4];
            sAT[(col4+0)*68 + nn] = av.x;
            sAT[(col4+1)*68 + nn] = av.y;
            sAT[(col4+2)*68 + nn] = av.z;
            sAT[(col4+3)*68 + nn] = av.w;
        }
        // B tile: src[bt][m0+kk][f] (* mgate) -> sB[kk][f]
        #pragma unroll
        for (int i = 0; i < 4; i++){
            const int kk = row + 16*i;
            float4 bv = *(const float4*)&srcbt[(size_t)(m0+kk)*64 + col4];
            if (HAS_MGATE){
                const float g = mg[m0 + kk];
                bv.x *= g; bv.y *= g; bv.z *= g; bv.w *= g;
            }
            *(float4*)&sB[kk*68 + col4] = bv;
        }
        __syncthreads();
        #pragma unroll 8
        for (int kk = 0; kk < 64; kk++){
            const float4 a4 = *(const float4*)&sAT[kk*68 + row*4];
            const float4 b4 = *(const float4*)&sB [kk*68 + col4];
            const float aa[4] = {a4.x, a4.y, a4.z, a4.w};
            const float bb[4] = {b4.x, b4.y, b4.z, b4.w};
            #pragma unroll
            for (int i = 0; i < 4; i++)
                #pragma unroll
                for (int j = 0; j < 4; j++)
                    accr[i][j] = fmaf(aa[i], bb[j], accr[i][j]);
        }
        __syncthreads();
    }

    // optionally write the diffused state (needed as next step's source)
    if (WRITE_TMP){
        #pragma unroll
        for (int i = 0; i < 4; i++){
            const float4 v = make_float4(accr[i][0], accr[i][1], accr[i][2], accr[i][3]);
            *(float4*)&tmpout[((size_t)bt*1024 + n0 + row*4 + i)*64 + col4] = v;
        }
    }

    // stage next^T into sAT (safe: last loop iter ended with barrier)
    #pragma unroll
    for (int i = 0; i < 4; i++)
        #pragma unroll
        for (int j = 0; j < 4; j++)
            sAT[(col4+j)*68 + row*4 + i] = accr[i][j];
    __syncthreads();

    // lin[n][o] = sum_f next[n][f] * W[o][f]
    float lin[4][4] = {{0.f}};
    #pragma unroll 8
    for (int f = 0; f < 64; f++){
        const float4 a4 = *(const float4*)&sAT[f*68 + row*4];
        const float4 w4 = *(const float4*)&sWT[f*68 + col4];
        const float aa[4] = {a4.x, a4.y, a4.z, a4.w};
        const float ww[4] = {w4.x, w4.y, w4.z, w4.w};
        #pragma unroll
        for (int i = 0; i < 4; i++)
            #pragma unroll
            for (int j = 0; j < 4; j++)
                lin[i][j] = fmaf(aa[i], ww[j], lin[i][j]);
    }

    const float4 bsv = *(const float4*)&bias[col4];
    const float bb[4] = {bsv.x, bsv.y, bsv.z, bsv.w};
    #pragma unroll
    for (int i = 0; i < 4; i++){
        const size_t tok = (size_t)bt*1024 + n0 + row*4 + i;
        const float g = gates[tok*4 + branch];
        float4* p = (float4*)&acc[tok*64 + col4];
        float4 cur = *p;
        cur.x += g * (lin[i][0] + bb[0]);
        cur.y += g * (lin[i][1] + bb[1]);
        cur.z += g * (lin[i][2] + bb[2]);
        cur.w += g * (lin[i][3] + bb[3]);
        *p = cur;
    }
}

// ---------------------------------------------------------------------------
// Finalize: mixed = acc*scale; h = x + gelu(mixed); layernorm(h)*gamma+beta
// one wave per token
// ---------------------------------------------------------------------------
__global__ __launch_bounds__(256) void k_final(
    const float* __restrict__ x, const float* __restrict__ scale,
    const float* __restrict__ gamma, const float* __restrict__ beta,
    float* __restrict__ out)
{
    const int tid = threadIdx.x;
    const int w = tid >> 6, lane = tid & 63;
    const size_t tok  = (size_t)blockIdx.x*4 + w;
    const size_t base = tok*64 + lane;
    const float mixed = out[base] * scale[base];
    const float h = x[base] + gelu_exact(mixed);
    float mu = h;
    #pragma unroll
    for (int o = 32; o > 0; o >>= 1) mu += __shfl_xor(mu, o, 64);
    mu *= (1.0f/64.0f);
    const float d = h - mu;
    float v = d*d;
    #pragma unroll
    for (int o = 32; o > 0; o >>= 1) v += __shfl_xor(v, o, 64);
    v *= (1.0f/64.0f);
    out[base] = d * rsqrtf(v + LN_EPS) * gamma[lane] + beta[lane];
}

// ---------------------------------------------------------------------------
extern "C" void kernel_launch(void* const* d_in, const int* in_sizes, int n_in,
                              void* d_out, int out_size, void* d_ws, size_t ws_size,
                              hipStream_t stream)
{
    const float* x      = (const float*)d_in[0];
    const float* a_fwd  = (const float*)d_in[1];
    const float* ctx    = (const float*)d_in[2];
    const float* W_self = (const float*)d_in[3];
    const float* b_self = (const float*)d_in[4];
    const float* W_fwd  = (const float*)d_in[5];
    const float* b_fwd  = (const float*)d_in[6];
    const float* W_bwd  = (const float*)d_in[7];
    const float* b_bwd  = (const float*)d_in[8];
    const float* W_adp  = (const float*)d_in[9];
    const float* b_adp  = (const float*)d_in[10];
    const float* Wg1    = (const float*)d_in[11];
    const float* bg1    = (const float*)d_in[12];
    const float* Wg2    = (const float*)d_in[13];
    const float* bg2    = (const float*)d_in[14];
    const float* Ws1    = (const float*)d_in[15];
    const float* bs1    = (const float*)d_in[16];
    const float* Ws2    = (const float*)d_in[17];
    const float* bs2    = (const float*)d_in[18];
    const float* W_src  = (const float*)d_in[19];
    const float* b_src  = (const float*)d_in[20];
    const float* W_dst  = (const float*)d_in[21];
    const float* b_dst  = (const float*)d_in[22];
    const float* emb_src= (const float*)d_in[23];
    const float* emb_dst= (const float*)d_in[24];
    const float* gamma  = (const float*)d_in[25];
    const float* beta   = (const float*)d_in[26];

    float* out = (float*)d_out;
    float* ws  = (float*)d_ws;
    float* aadp  = ws;                       // 1,048,576
    float* abwd  = ws + 1048576;             // 1,048,576
    float* tmp   = ws + 2097152;             // 25,165,824
    float* scale = ws + 27262976;            // 25,165,824
    float* gates = ws + 52428800;            // 1,572,864
    float* srcg  = ws + 54001664;            //   393,216
    float* dstg  = ws + 54394880;            //   393,216

    k_adp      <<<1024, 256, 0, stream>>>(emb_src, emb_dst, aadp);
    k_transpose<<<dim3(32,32), 256, 0, stream>>>(a_fwd, abwd);
    k_gating   <<<6144, 256, 0, stream>>>(x, ctx, Wg1,bg1, Wg2,bg2, Ws1,bs1, Ws2,bs2,
                                          W_src,b_src, W_dst,b_dst, W_self,b_self,
                                          gates, scale, srcg, dstg, out);
    dim3 g(16, 384);
    k_diff<true ,true ><<<g,256,0,stream>>>(a_fwd, x,   dstg,    W_fwd,      b_fwd,    gates, 1, out, tmp);
    k_diff<false,false><<<g,256,0,stream>>>(a_fwd, tmp, nullptr, W_fwd+4096, b_fwd+64, gates, 1, out, nullptr);
    k_diff<true ,true ><<<g,256,0,stream>>>(abwd,  x,   srcg,    W_bwd,      b_bwd,    gates, 2, out, tmp);
    k_diff<false,false><<<g,256,0,stream>>>(abwd,  tmp, nullptr, W_bwd+4096, b_bwd+64, gates, 2, out, nullptr);
    k_diff<false,true ><<<g,256,0,stream>>>(aadp,  x,   nullptr, W_adp,      b_adp,    gates, 3, out, tmp);
    k_diff<false,false><<<g,256,0,stream>>>(aadp,  tmp, nullptr, W_adp+4096, b_adp+64, gates, 3, out, nullptr);
    k_final    <<<98304, 256, 0, stream>>>(x, scale, gamma, beta, out);
}

// Round 2
// 1333.045 us; speedup vs baseline: 3.9980x; 3.9980x over previous
//
#include <hip/hip_runtime.h>
#include <math.h>

typedef unsigned short u16;
typedef short short8 __attribute__((ext_vector_type(8)));
typedef float f32x4 __attribute__((ext_vector_type(4)));

#define LN_EPS 1e-5f

__device__ __forceinline__ float gelu_exact(float x){
    return 0.5f * x * (1.0f + erff(x * 0.70710678118654752f));
}
__device__ __forceinline__ float sigmoidf_(float x){
    return 1.0f / (1.0f + __expf(-x));
}
__device__ __forceinline__ u16 f2bf(float f){            // RTNE f32->bf16
    unsigned u = __float_as_uint(f);
    u += 0x7fffu + ((u >> 16) & 1u);
    return (u16)(u >> 16);
}
__device__ __forceinline__ float b2f(u16 u){
    return __uint_as_float(((unsigned)u) << 16);
}

#define GLLDS(gp, lp) __builtin_amdgcn_global_load_lds( \
    (const __attribute__((address_space(1))) unsigned int*)(const void*)(gp), \
    (__attribute__((address_space(3))) unsigned int*)(void*)(lp), 16, 0, 0)

// ---------------------------------------------------------------------------
// a_adp = softmax(relu(emb_src @ emb_dst^T)) -> bf16 [1024][1024]
// ---------------------------------------------------------------------------
__global__ __launch_bounds__(256) void k_adp(const float* __restrict__ es,
                                             const float* __restrict__ ed,
                                             u16* __restrict__ aadp){
    __shared__ float srow[1024];
    __shared__ float s_es[16];
    __shared__ float sredm[4];
    __shared__ float sreds[4];
    const int n   = blockIdx.x;
    const int tid = threadIdx.x;
    const int wid = tid >> 6, lane = tid & 63;
    if (tid < 16) s_es[tid] = es[n*16 + tid];
    __syncthreads();
    float lmax = 0.0f;
    for (int m = tid; m < 1024; m += 256){
        const float* edm = ed + m*16;
        float z = 0.f;
        #pragma unroll
        for (int r = 0; r < 16; r++) z = fmaf(s_es[r], edm[r], z);
        z = fmaxf(z, 0.0f);
        srow[m] = z;
        lmax = fmaxf(lmax, z);
    }
    #pragma unroll
    for (int o = 32; o > 0; o >>= 1) lmax = fmaxf(lmax, __shfl_xor(lmax, o, 64));
    if (lane == 0) sredm[wid] = lmax;
    __syncthreads();
    const float tmax = fmaxf(fmaxf(sredm[0], sredm[1]), fmaxf(sredm[2], sredm[3]));
    float lsum = 0.f;
    for (int m = tid; m < 1024; m += 256){
        float e = expf(srow[m] - tmax);
        srow[m] = e;
        lsum += e;
    }
    #pragma unroll
    for (int o = 32; o > 0; o >>= 1) lsum += __shfl_xor(lsum, o, 64);
    if (lane == 0) sreds[wid] = lsum;
    __syncthreads();
    const float inv = 1.0f / (sreds[0] + sreds[1] + sreds[2] + sreds[3]);
    for (int m = tid; m < 1024; m += 256) aadp[(size_t)n*1024 + m] = f2bf(srow[m] * inv);
}

// ---------------------------------------------------------------------------
// a_fwd f32 -> bf16 (elementwise)
// ---------------------------------------------------------------------------
__global__ __launch_bounds__(256) void k_cvt(const float* __restrict__ in,
                                             u16* __restrict__ out){
    const int i = blockIdx.x*256 + threadIdx.x;
    const float4 v = ((const float4*)in)[i];
    ushort4 o;
    o.x = f2bf(v.x); o.y = f2bf(v.y); o.z = f2bf(v.z); o.w = f2bf(v.w);
    ((ushort4*)out)[i] = o;
}

// ---------------------------------------------------------------------------
// abwd[n][m] = bf16(a_fwd[m][n])
// ---------------------------------------------------------------------------
__global__ __launch_bounds__(256) void k_bwd(const float* __restrict__ a,
                                             u16* __restrict__ at){
    __shared__ float t[32][33];
    const int bx = blockIdx.x*32, by = blockIdx.y*32;
    const int tx = threadIdx.x & 31, ty = threadIdx.x >> 5;
    #pragma unroll
    for (int i = 0; i < 4; i++)
        t[ty + 8*i][tx] = a[(size_t)(by + ty + 8*i)*1024 + bx + tx];
    __syncthreads();
    #pragma unroll
    for (int i = 0; i < 4; i++)
        at[(size_t)(bx + ty + 8*i)*1024 + by + tx] = f2bf(t[tx][ty + 8*i]);
}

// ---------------------------------------------------------------------------
// Gating kernel (f32 VALU): gates[4], scale(bf16), src/dst gates,
// acc = g0*(x@W_self^T+b_self) written to d_out.
// ---------------------------------------------------------------------------
__global__ __launch_bounds__(256, 2) void k_gating(
    const float* __restrict__ x,    const float* __restrict__ ctx,
    const float* __restrict__ Wg1,  const float* __restrict__ bg1,
    const float* __restrict__ Wg2,  const float* __restrict__ bg2,
    const float* __restrict__ Ws1,  const float* __restrict__ bs1,
    const float* __restrict__ Ws2,  const float* __restrict__ bs2,
    const float* __restrict__ Wsrc, const float* __restrict__ bsrc,
    const float* __restrict__ Wdst, const float* __restrict__ bdst,
    const float* __restrict__ Wself,const float* __restrict__ bself,
    float* __restrict__ gates, u16* __restrict__ scaleb,
    float* __restrict__ srcg,  float* __restrict__ dstg,
    float* __restrict__ acc)
{
    __shared__ float sWg1[64*65];
    __shared__ float sWs1[64*65];
    __shared__ float sWs2[64*65];
    __shared__ float sWself[64*65];
    __shared__ float sWg2[4*64];
    __shared__ float sTok[16][64];
    __shared__ float sHg[16][64];
    __shared__ float sHs[16][64];
    __shared__ float sG[16];

    const int tid = threadIdx.x;
    for (int idx = tid; idx < 4096; idx += 256){
        const int o = idx >> 6, k = idx & 63;
        sWg1[o*65+k]   = Wg1[idx];
        sWs1[o*65+k]   = Ws1[idx];
        sWs2[o*65+k]   = Ws2[idx];
        sWself[o*65+k] = Wself[idx];
    }
    sWg2[tid] = Wg2[tid];
    __syncthreads();

    const int w = tid >> 6, lane = tid & 63;
    const float bg1v = bg1[lane], bs1v = bs1[lane], bs2v = bs2[lane], bselfv = bself[lane];
    const float wsrcv = Wsrc[lane], wdstv = Wdst[lane];
    const float bsrcv = bsrc[0],  bdstv = bdst[0];

    for (int pass = 0; pass < 4; pass++){
        const int tokbase = blockIdx.x*64 + pass*16 + w*4;
        #pragma unroll
        for (int t = 0; t < 4; t++)
            sTok[w*4+t][lane] = ctx[(size_t)(tokbase+t)*64 + lane];
        __syncthreads();
        float hg[4] = {bg1v, bg1v, bg1v, bg1v};
        float hs[4] = {bs1v, bs1v, bs1v, bs1v};
        for (int k = 0; k < 64; k++){
            const float wg = sWg1[lane*65+k];
            const float wsv = sWs1[lane*65+k];
            #pragma unroll
            for (int t = 0; t < 4; t++){
                const float c = sTok[w*4+t][k];
                hg[t] = fmaf(c, wg,  hg[t]);
                hs[t] = fmaf(c, wsv, hs[t]);
            }
        }
        #pragma unroll
        for (int t = 0; t < 4; t++){
            sHg[w*4+t][lane] = gelu_exact(hg[t]);
            sHs[w*4+t][lane] = gelu_exact(hs[t]);
        }
        #pragma unroll
        for (int t = 0; t < 4; t++){
            const float c = sTok[w*4+t][lane];
            float ps = c * wsrcv, pd = c * wdstv;
            #pragma unroll
            for (int o = 32; o > 0; o >>= 1){
                ps += __shfl_xor(ps, o, 64);
                pd += __shfl_xor(pd, o, 64);
            }
            if (lane == 0){
                srcg[tokbase+t] = sigmoidf_(ps + bsrcv);
                dstg[tokbase+t] = sigmoidf_(pd + bdstv);
            }
        }
        __syncthreads();
        {
            float sc[4] = {bs2v, bs2v, bs2v, bs2v};
            for (int k = 0; k < 64; k++){
                const float wv = sWs2[lane*65+k];
                #pragma unroll
                for (int t = 0; t < 4; t++) sc[t] = fmaf(sHs[w*4+t][k], wv, sc[t]);
            }
            #pragma unroll
            for (int t = 0; t < 4; t++)
                scaleb[(size_t)(tokbase+t)*64 + lane] = f2bf(sigmoidf_(sc[t]));
        }
        if (lane < 16){
            const int t = lane >> 2, j = lane & 3;
            float g = bg2[j];
            for (int k = 0; k < 64; k++) g = fmaf(sHg[w*4+t][k], sWg2[j*64+k], g);
            g = sigmoidf_(g);
            gates[(size_t)(tokbase+t)*4 + j] = g;
            if (j == 0) sG[w*4+t] = g;
        }
        #pragma unroll
        for (int t = 0; t < 4; t++)
            sTok[w*4+t][lane] = x[(size_t)(tokbase+t)*64 + lane];
        __syncthreads();
        float sv[4] = {bselfv, bselfv, bselfv, bselfv};
        for (int k = 0; k < 64; k++){
            const float wv = sWself[lane*65+k];
            #pragma unroll
            for (int t = 0; t < 4; t++) sv[t] = fmaf(sTok[w*4+t][k], wv, sv[t]);
        }
        #pragma unroll
        for (int t = 0; t < 4; t++)
            acc[(size_t)(tokbase+t)*64 + lane] = sG[w*4+t] * sv[t];
        __syncthreads();
    }
}

// ---------------------------------------------------------------------------
// Transpose x to feature-major bf16, 3 gated variants:
//   xTp[bt][f][m]=x, xTd=x*dstg[m], xTs=x*srcg[m]
// ---------------------------------------------------------------------------
__global__ __launch_bounds__(256) void k_xpose(
    const float* __restrict__ x, const float* __restrict__ srcg,
    const float* __restrict__ dstg,
    u16* __restrict__ xTp, u16* __restrict__ xTd, u16* __restrict__ xTs)
{
    __shared__ float sT[64][65];
    __shared__ float sg[64], dg[64];
    const int bt = blockIdx.y, m0 = blockIdx.x*64;
    const int tid = threadIdx.x;
    #pragma unroll
    for (int i = 0; i < 4; i++){
        const int idx = i*256 + tid;
        const int row = idx >> 4, c4 = (idx & 15)*4;
        const float4 v = *(const float4*)&x[((size_t)bt*1024 + m0 + row)*64 + c4];
        sT[c4+0][row] = v.x; sT[c4+1][row] = v.y;
        sT[c4+2][row] = v.z; sT[c4+3][row] = v.w;
    }
    if (tid < 64){
        sg[tid] = srcg[(size_t)bt*1024 + m0 + tid];
        dg[tid] = dstg[(size_t)bt*1024 + m0 + tid];
    }
    __syncthreads();
    const size_t obase = (size_t)bt*65536 + m0;
    for (int i = tid; i < 4096; i += 256){
        const int f = i >> 6, m = i & 63;
        const float v = sT[f][m];
        const size_t o = obase + (size_t)f*1024 + m;
        xTp[o] = f2bf(v);
        xTd[o] = f2bf(v * dg[m]);
        xTs[o] = f2bf(v * sg[m]);
    }
}

// ---------------------------------------------------------------------------
// MFMA diffusion GEMM + fused linear/gate epilogue.
//   y[n,:] = adj[n,:] @ srcT^T    (K=1024, bf16 MFMA, f32 accum)
//   if WRITE_TMP: tmpT[bt][f][n] = bf16(y)
//   acc[bt,n,o] += gates[bt,n][branch] * (y @ W^T + bias)[o]
// BM=256, BN=64, BK=64; 4 waves, 64x64 wave tile, mfma_f32_16x16x32_bf16.
// T2 swizzle: 16B slot kb stored/read at kb^(row&7); pre-swizzled global src.
// ---------------------------------------------------------------------------
template<bool WRITE_TMP>
__global__ __launch_bounds__(256, 2) void k_diffmm(
    const u16* __restrict__ adj,  const u16* __restrict__ srcT,
    const float* __restrict__ W,  const float* __restrict__ bias,
    const float* __restrict__ gates, const int branch,
    float* __restrict__ acc, u16* __restrict__ tmpT)
{
    __shared__ u16 sA[2][256*64];   // 2 x 32 KB
    __shared__ u16 sB[2][64*64];    // 2 x 8 KB

    const int tid = threadIdx.x;
    const int bt  = blockIdx.y;
    const int n0  = blockIdx.x * 256;
    const int wv  = tid >> 6, lane = tid & 63;
    const int lr  = lane & 15, lg = lane >> 4;
    const int wrow0 = wv * 64;

    const u16* asrc = adj  + (size_t)n0 * 1024;
    const u16* bsrc = srcT + (size_t)bt * 65536;

    auto stage = [&](int buf, int kt){
        const int m0 = kt * 64;
        #pragma unroll
        for (int i = 0; i < 8; i++){
            const int s = i*256 + tid;
            const int row = s >> 3, kbp = s & 7;
            const int kb = kbp ^ (row & 7);
            GLLDS(asrc + (size_t)row*1024 + m0 + kb*8, &sA[buf][s*8]);
        }
        #pragma unroll
        for (int i = 0; i < 2; i++){
            const int s = i*256 + tid;
            const int row = s >> 3, kbp = s & 7;
            const int kb = kbp ^ (row & 7);
            GLLDS(bsrc + (size_t)row*1024 + m0 + kb*8, &sB[buf][s*8]);
        }
    };

    const f32x4 z4 = {0.f, 0.f, 0.f, 0.f};
    f32x4 c[4][4];
    #pragma unroll
    for (int m = 0; m < 4; m++)
        #pragma unroll
        for (int n = 0; n < 4; n++) c[m][n] = z4;

    stage(0, 0);
    asm volatile("s_waitcnt vmcnt(0)" ::: "memory");
    __syncthreads();

    int cur = 0;
    for (int kt = 0; kt < 16; kt++){
        if (kt < 15) stage(cur ^ 1, kt + 1);
        const u16* A = sA[cur];
        const u16* B = sB[cur];
        short8 af[2][4], bfr[2][4];
        #pragma unroll
        for (int kk = 0; kk < 2; kk++){
            const int kb = lg + kk*4;
            #pragma unroll
            for (int m = 0; m < 4; m++){
                const int row = wrow0 + m*16 + lr;
                af[kk][m] = *(const short8*)&A[row*64 + ((kb ^ (row & 7)) << 3)];
            }
            #pragma unroll
            for (int n = 0; n < 4; n++){
                const int fr = n*16 + lr;
                bfr[kk][n] = *(const short8*)&B[fr*64 + ((kb ^ (fr & 7)) << 3)];
            }
        }
        #pragma unroll
        for (int kk = 0; kk < 2; kk++)
            #pragma unroll
            for (int m = 0; m < 4; m++)
                #pragma unroll
                for (int n = 0; n < 4; n++)
                    c[m][n] = __builtin_amdgcn_mfma_f32_16x16x32_bf16(
                        af[kk][m], bfr[kk][n], c[m][n], 0, 0, 0);
        asm volatile("s_waitcnt vmcnt(0)" ::: "memory");
        __syncthreads();
        cur ^= 1;
    }

    // write diffused state (transposed bf16) for next step
    if (WRITE_TMP){
        #pragma unroll
        for (int m = 0; m < 4; m++)
            #pragma unroll
            for (int n = 0; n < 4; n++){
                const int f    = n*16 + lr;
                const int node = n0 + wrow0 + m*16 + lg*4;
                ushort4 v;
                v.x = f2bf(c[m][n][0]); v.y = f2bf(c[m][n][1]);
                v.z = f2bf(c[m][n][2]); v.w = f2bf(c[m][n][3]);
                *(ushort4*)&tmpT[(size_t)bt*65536 + (size_t)f*1024 + node] = v;
            }
    }

    // y -> LDS (bf16, swizzled), W -> LDS (bf16, swizzled); reuse buffers
    u16* yT = &sA[0][0];     // 256 x 64
    u16* sW = &sB[0][0];     // 64 x 64
    #pragma unroll
    for (int m = 0; m < 4; m++)
        #pragma unroll
        for (int n = 0; n < 4; n++){
            const int f = n*16 + lr;
            #pragma unroll
            for (int r = 0; r < 4; r++){
                const int row = wrow0 + m*16 + lg*4 + r;
                yT[row*64 + (((f >> 3) ^ (row & 7)) << 3) + (f & 7)] = f2bf(c[m][n][r]);
            }
        }
    for (int i = tid; i < 4096; i += 256){
        const int o = i >> 6, f = i & 63;
        sW[o*64 + (((f >> 3) ^ (o & 7)) << 3) + (f & 7)] = f2bf(W[i]);
    }
    __syncthreads();

    // lin = y @ W^T via MFMA (K = 64)
    f32x4 lin[4][4];
    #pragma unroll
    for (int m = 0; m < 4; m++)
        #pragma unroll
        for (int n = 0; n < 4; n++) lin[m][n] = z4;
    #pragma unroll
    for (int kk = 0; kk < 2; kk++){
        const int kb = lg + kk*4;
        short8 ya[4], wb[4];
        #pragma unroll
        for (int m = 0; m < 4; m++){
            const int row = wrow0 + m*16 + lr;
            ya[m] = *(const short8*)&yT[row*64 + ((kb ^ (row & 7)) << 3)];
        }
        #pragma unroll
        for (int n = 0; n < 4; n++){
            const int o = n*16 + lr;
            wb[n] = *(const short8*)&sW[o*64 + ((kb ^ (o & 7)) << 3)];
        }
        #pragma unroll
        for (int m = 0; m < 4; m++)
            #pragma unroll
            for (int n = 0; n < 4; n++)
                lin[m][n] = __builtin_amdgcn_mfma_f32_16x16x32_bf16(
                    ya[m], wb[n], lin[m][n], 0, 0, 0);
    }

    // acc += g * (lin + bias)
    #pragma unroll
    for (int m = 0; m < 4; m++){
        float g[4];
        #pragma unroll
        for (int r = 0; r < 4; r++){
            const int node = n0 + wrow0 + m*16 + lg*4 + r;
            g[r] = gates[((size_t)bt*1024 + node)*4 + branch];
        }
        #pragma unroll
        for (int n = 0; n < 4; n++){
            const int f  = n*16 + lr;
            const float bv = bias[f];
            #pragma unroll
            for (int r = 0; r < 4; r++){
                const int node = n0 + wrow0 + m*16 + lg*4 + r;
                float* p = &acc[((size_t)bt*1024 + node)*64 + f];
                *p += g[r] * (lin[m][n][r] + bv);
            }
        }
    }
}

// ---------------------------------------------------------------------------
// Finalize: mixed = acc*scale; h = x + gelu(mixed); layernorm
// ---------------------------------------------------------------------------
__global__ __launch_bounds__(256) void k_final(
    const float* __restrict__ x, const u16* __restrict__ scaleb,
    const float* __restrict__ gamma, const float* __restrict__ beta,
    float* __restrict__ out)
{
    const int tid = threadIdx.x;
    const int w = tid >> 6, lane = tid & 63;
    const size_t tok  = (size_t)blockIdx.x*4 + w;
    const size_t base = tok*64 + lane;
    const float mixed = out[base] * b2f(scaleb[base]);
    const float h = x[base] + gelu_exact(mixed);
    float mu = h;
    #pragma unroll
    for (int o = 32; o > 0; o >>= 1) mu += __shfl_xor(mu, o, 64);
    mu *= (1.0f/64.0f);
    const float d = h - mu;
    float v = d*d;
    #pragma unroll
    for (int o = 32; o > 0; o >>= 1) v += __shfl_xor(v, o, 64);
    v *= (1.0f/64.0f);
    out[base] = d * rsqrtf(v + LN_EPS) * gamma[lane] + beta[lane];
}

// ---------------------------------------------------------------------------
extern "C" void kernel_launch(void* const* d_in, const int* in_sizes, int n_in,
                              void* d_out, int out_size, void* d_ws, size_t ws_size,
                              hipStream_t stream)
{
    const float* x      = (const float*)d_in[0];
    const float* a_fwd  = (const float*)d_in[1];
    const float* ctx    = (const float*)d_in[2];
    const float* W_self = (const float*)d_in[3];
    const float* b_self = (const float*)d_in[4];
    const float* W_fwd  = (const float*)d_in[5];
    const float* b_fwd  = (const float*)d_in[6];
    const float* W_bwd  = (const float*)d_in[7];
    const float* b_bwd  = (const float*)d_in[8];
    const float* W_adp  = (const float*)d_in[9];
    const float* b_adp  = (const float*)d_in[10];
    const float* Wg1    = (const float*)d_in[11];
    const float* bg1    = (const float*)d_in[12];
    const float* Wg2    = (const float*)d_in[13];
    const float* bg2    = (const float*)d_in[14];
    const float* Ws1    = (const float*)d_in[15];
    const float* bs1    = (const float*)d_in[16];
    const float* Ws2    = (const float*)d_in[17];
    const float* bs2    = (const float*)d_in[18];
    const float* W_src  = (const float*)d_in[19];
    const float* b_src  = (const float*)d_in[20];
    const float* W_dst  = (const float*)d_in[21];
    const float* b_dst  = (const float*)d_in[22];
    const float* emb_src= (const float*)d_in[23];
    const float* emb_dst= (const float*)d_in[24];
    const float* gamma  = (const float*)d_in[25];
    const float* beta   = (const float*)d_in[26];

    float* out = (float*)d_out;
    char*  w   = (char*)d_ws;
    const size_t MB48 = 50331648ull;
    u16* afwd_bf = (u16*)(w);
    u16* abwd_bf = (u16*)(w + 2097152ull);
    u16* aadp_bf = (u16*)(w + 4194304ull);
    u16* xTp     = (u16*)(w + 6291456ull);
    u16* xTd     = (u16*)(w + 6291456ull + 1*MB48);
    u16* xTs     = (u16*)(w + 6291456ull + 2*MB48);
    u16* tmpT    = (u16*)(w + 6291456ull + 3*MB48);
    u16* scaleb  = (u16*)(w + 6291456ull + 4*MB48);
    float* gates = (float*)(w + 6291456ull + 5*MB48);
    float* srcg  = gates + 1572864;
    float* dstg  = srcg + 393216;

    k_adp   <<<1024, 256, 0, stream>>>(emb_src, emb_dst, aadp_bf);
    k_cvt   <<<1024, 256, 0, stream>>>(a_fwd, afwd_bf);
    k_bwd   <<<dim3(32,32), 256, 0, stream>>>(a_fwd, abwd_bf);
    k_gating<<<6144, 256, 0, stream>>>(x, ctx, Wg1,bg1, Wg2,bg2, Ws1,bs1, Ws2,bs2,
                                       W_src,b_src, W_dst,b_dst, W_self,b_self,
                                       gates, scaleb, srcg, dstg, out);
    k_xpose <<<dim3(16,384), 256, 0, stream>>>(x, srcg, dstg, xTp, xTd, xTs);

    dim3 g(4, 384);
    k_diffmm<true ><<<g,256,0,stream>>>(afwd_bf, xTd,  W_fwd,      b_fwd,    gates, 1, out, tmpT);
    k_diffmm<false><<<g,256,0,stream>>>(afwd_bf, tmpT, W_fwd+4096, b_fwd+64, gates, 1, out, tmpT);
    k_diffmm<true ><<<g,256,0,stream>>>(abwd_bf, xTs,  W_bwd,      b_bwd,    gates, 2, out, tmpT);
    k_diffmm<false><<<g,256,0,stream>>>(abwd_bf, tmpT, W_bwd+4096, b_bwd+64, gates, 2, out, tmpT);
    k_diffmm<true ><<<g,256,0,stream>>>(aadp_bf, xTp,  W_adp,      b_adp,    gates, 3, out, tmpT);
    k_diffmm<false><<<g,256,0,stream>>>(aadp_bf, tmpT, W_adp+4096, b_adp+64, gates, 3, out, tmpT);

    k_final <<<98304, 256, 0, stream>>>(x, scaleb, gamma, beta, out);
}

// Round 3
// 1159.199 us; speedup vs baseline: 4.5976x; 1.1500x over previous
//
#include <hip/hip_runtime.h>
#include <math.h>

typedef unsigned short u16;
typedef short short8 __attribute__((ext_vector_type(8)));
typedef float f32x4 __attribute__((ext_vector_type(4)));

#define LN_EPS 1e-5f

__device__ __forceinline__ float gelu_exact(float x){
    return 0.5f * x * (1.0f + erff(x * 0.70710678118654752f));
}
__device__ __forceinline__ float sigmoidf_(float x){
    return 1.0f / (1.0f + __expf(-x));
}
__device__ __forceinline__ u16 f2bf(float f){            // RTNE f32->bf16
    unsigned u = __float_as_uint(f);
    u += 0x7fffu + ((u >> 16) & 1u);
    return (u16)(u >> 16);
}
__device__ __forceinline__ float b2f(u16 u){
    return __uint_as_float(((unsigned)u) << 16);
}

#define GLLDS(gp, lp) __builtin_amdgcn_global_load_lds( \
    (const __attribute__((address_space(1))) unsigned int*)(const void*)(gp), \
    (__attribute__((address_space(3))) unsigned int*)(void*)(lp), 16, 0, 0)

// ---------------------------------------------------------------------------
// a_adp = softmax(relu(emb_src @ emb_dst^T)) -> bf16 [1024][1024]
// ---------------------------------------------------------------------------
__global__ __launch_bounds__(256) void k_adp(const float* __restrict__ es,
                                             const float* __restrict__ ed,
                                             u16* __restrict__ aadp){
    __shared__ float srow[1024];
    __shared__ float s_es[16];
    __shared__ float sredm[4];
    __shared__ float sreds[4];
    const int n   = blockIdx.x;
    const int tid = threadIdx.x;
    const int wid = tid >> 6, lane = tid & 63;
    if (tid < 16) s_es[tid] = es[n*16 + tid];
    __syncthreads();
    float lmax = 0.0f;
    for (int m = tid; m < 1024; m += 256){
        const float* edm = ed + m*16;
        float z = 0.f;
        #pragma unroll
        for (int r = 0; r < 16; r++) z = fmaf(s_es[r], edm[r], z);
        z = fmaxf(z, 0.0f);
        srow[m] = z;
        lmax = fmaxf(lmax, z);
    }
    #pragma unroll
    for (int o = 32; o > 0; o >>= 1) lmax = fmaxf(lmax, __shfl_xor(lmax, o, 64));
    if (lane == 0) sredm[wid] = lmax;
    __syncthreads();
    const float tmax = fmaxf(fmaxf(sredm[0], sredm[1]), fmaxf(sredm[2], sredm[3]));
    float lsum = 0.f;
    for (int m = tid; m < 1024; m += 256){
        float e = expf(srow[m] - tmax);
        srow[m] = e;
        lsum += e;
    }
    #pragma unroll
    for (int o = 32; o > 0; o >>= 1) lsum += __shfl_xor(lsum, o, 64);
    if (lane == 0) sreds[wid] = lsum;
    __syncthreads();
    const float inv = 1.0f / (sreds[0] + sreds[1] + sreds[2] + sreds[3]);
    for (int m = tid; m < 1024; m += 256) aadp[(size_t)n*1024 + m] = f2bf(srow[m] * inv);
}

// ---------------------------------------------------------------------------
// a_fwd f32 -> bf16 (elementwise)
// ---------------------------------------------------------------------------
__global__ __launch_bounds__(256) void k_cvt(const float* __restrict__ in,
                                             u16* __restrict__ out){
    const int i = blockIdx.x*256 + threadIdx.x;
    const float4 v = ((const float4*)in)[i];
    ushort4 o;
    o.x = f2bf(v.x); o.y = f2bf(v.y); o.z = f2bf(v.z); o.w = f2bf(v.w);
    ((ushort4*)out)[i] = o;
}

// ---------------------------------------------------------------------------
// abwd[n][m] = bf16(a_fwd[m][n])
// ---------------------------------------------------------------------------
__global__ __launch_bounds__(256) void k_bwd(const float* __restrict__ a,
                                             u16* __restrict__ at){
    __shared__ float t[32][33];
    const int bx = blockIdx.x*32, by = blockIdx.y*32;
    const int tx = threadIdx.x & 31, ty = threadIdx.x >> 5;
    #pragma unroll
    for (int i = 0; i < 4; i++)
        t[ty + 8*i][tx] = a[(size_t)(by + ty + 8*i)*1024 + bx + tx];
    __syncthreads();
    #pragma unroll
    for (int i = 0; i < 4; i++)
        at[(size_t)(bx + ty + 8*i)*1024 + by + tx] = f2bf(t[tx][ty + 8*i]);
}

// ---------------------------------------------------------------------------
// MFMA gating kernel. Block = 256 tokens, 4 waves x 64 tokens.
// Computes per token: hg=gelu(ctx@Wg1^T+b), hs=gelu(ctx@Ws1^T+b),
//   gates=sig(hg@Wg2^T+b), scale=sig(hs@Ws2^T+b), srcg/dstg=sig(ctx.Wsrc/dst),
//   acc=g0*(x@Wself^T+b)  (written to d_out)
// Also emits xTp/xTd/xTs = bf16 feature-major (gated) transposes of x.
// Activations staged bf16 in LDS, XOR-swizzled (kb ^ (row&7)); weights loaded
// as B-fragments from global (f32->bf16 in-register, L2-resident).
// ---------------------------------------------------------------------------
__global__ __launch_bounds__(256, 2) void k_gating(
    const float* __restrict__ x,    const float* __restrict__ ctx,
    const float* __restrict__ Wg1,  const float* __restrict__ bg1,
    const float* __restrict__ Wg2,  const float* __restrict__ bg2,
    const float* __restrict__ Ws1,  const float* __restrict__ bs1,
    const float* __restrict__ Ws2,  const float* __restrict__ bs2,
    const float* __restrict__ Wsrc, const float* __restrict__ bsrc,
    const float* __restrict__ Wdst, const float* __restrict__ bdst,
    const float* __restrict__ Wself,const float* __restrict__ bself,
    float* __restrict__ gates, u16* __restrict__ scaleb,
    float* __restrict__ acc,
    u16* __restrict__ xTp, u16* __restrict__ xTd, u16* __restrict__ xTs)
{
    __shared__ u16 H1[16384];      // 32 KB: ctx -> hs -> scale-repack
    __shared__ u16 H2[16384];      // 32 KB: hg  -> x
    __shared__ float sgate[256], dgate[256];

    const int tid  = threadIdx.x;
    const int wv   = tid >> 6, lane = tid & 63;
    const int lr   = lane & 15, lg = lane >> 4;
    const int wtok = wv * 64;
    const int tokbase = blockIdx.x * 256;
    const int bt = blockIdx.x >> 2;
    const int n0 = (blockIdx.x & 3) * 256;

    // cooperative stage of a 256x64 f32 tile -> bf16 swizzled LDS
    auto stage_coop = [&](u16* H, const float* g){
        #pragma unroll
        for (int i = 0; i < 16; i++){
            const int fid = i*256 + tid;
            const int t = fid >> 4, q = fid & 15;
            const float4 v = *(const float4*)&g[(size_t)t*64 + q*4];
            ushort4 s;
            s.x = f2bf(v.x); s.y = f2bf(v.y); s.z = f2bf(v.z); s.w = f2bf(v.w);
            *(ushort4*)&H[t*64 + ((((q>>1) ^ (t & 7)) << 3) | ((q & 1)*4))] = s;
        }
    };
    auto afrag = [&](const u16* H, int row, int kb)->short8{
        return *(const short8*)&H[wv*4096 + row*64 + ((kb ^ (row & 7)) << 3)];
    };
    auto wfrag = [&](const float* W, int o, int kb8)->short8{
        const float4 a = *(const float4*)&W[o*64 + kb8];
        const float4 b = *(const float4*)&W[o*64 + kb8 + 4];
        short8 s;
        s[0]=f2bf(a.x); s[1]=f2bf(a.y); s[2]=f2bf(a.z); s[3]=f2bf(a.w);
        s[4]=f2bf(b.x); s[5]=f2bf(b.y); s[6]=f2bf(b.z); s[7]=f2bf(b.w);
        return s;
    };
    auto gemm64 = [&](const u16* Hs, const float* W, const float* bias, f32x4 (&c)[4][4]){
        #pragma unroll
        for (int n = 0; n < 4; n++){
            const float bv = bias[n*16 + lr];
            #pragma unroll
            for (int m = 0; m < 4; m++){ f32x4 t = {bv,bv,bv,bv}; c[m][n] = t; }
        }
        #pragma unroll
        for (int kk = 0; kk < 2; kk++){
            short8 a[4];
            #pragma unroll
            for (int m = 0; m < 4; m++) a[m] = afrag(Hs, m*16 + lr, kk*4 + lg);
            #pragma unroll
            for (int n = 0; n < 4; n++){
                const short8 w = wfrag(W, n*16 + lr, kk*32 + lg*8);
                #pragma unroll
                for (int m = 0; m < 4; m++)
                    c[m][n] = __builtin_amdgcn_mfma_f32_16x16x32_bf16(a[m], w, c[m][n], 0,0,0);
            }
        }
    };
    auto storeH = [&](u16* Hd, f32x4 (&c)[4][4]){
        #pragma unroll
        for (int m = 0; m < 4; m++)
            #pragma unroll
            for (int n = 0; n < 4; n++){
                const int f = n*16 + lr;
                #pragma unroll
                for (int r = 0; r < 4; r++){
                    const int t = m*16 + lg*4 + r;
                    Hd[wv*4096 + t*64 + ((((f>>3) ^ (t & 7)) << 3) | (f & 7))] = f2bf(c[m][n][r]);
                }
            }
    };

    stage_coop(H1, ctx + (size_t)tokbase*64);
    __syncthreads();

    f32x4 c[4][4];

    // hg = gelu(ctx @ Wg1^T + bg1) -> H2
    gemm64(H1, Wg1, bg1, c);
    #pragma unroll
    for (int m = 0; m < 4; m++)
        #pragma unroll
        for (int n = 0; n < 4; n++)
            #pragma unroll
            for (int r = 0; r < 4; r++) c[m][n][r] = gelu_exact(c[m][n][r]);
    storeH(H2, c);

    // src/dst gates: ctx @ [Wsrc;Wdst;0...]^T  (one 16-col GEMM)
    {
        f32x4 c2[4];
        const float bv = (lr == 0) ? bsrc[0] : (lr == 1 ? bdst[0] : 0.f);
        #pragma unroll
        for (int m = 0; m < 4; m++){ f32x4 t = {bv,bv,bv,bv}; c2[m] = t; }
        #pragma unroll
        for (int kk = 0; kk < 2; kk++){
            short8 a[4];
            #pragma unroll
            for (int m = 0; m < 4; m++) a[m] = afrag(H1, m*16 + lr, kk*4 + lg);
            short8 w = {0,0,0,0,0,0,0,0};
            if (lr == 0) w = wfrag(Wsrc, 0, kk*32 + lg*8);
            else if (lr == 1) w = wfrag(Wdst, 0, kk*32 + lg*8);
            #pragma unroll
            for (int m = 0; m < 4; m++)
                c2[m] = __builtin_amdgcn_mfma_f32_16x16x32_bf16(a[m], w, c2[m], 0,0,0);
        }
        #pragma unroll
        for (int m = 0; m < 4; m++)
            #pragma unroll
            for (int r = 0; r < 4; r++){
                const int t = wtok + m*16 + lg*4 + r;
                const float v = sigmoidf_(c2[m][r]);
                if (lr == 0) sgate[t] = v;
                if (lr == 1) dgate[t] = v;
            }
    }

    // hs = gelu(ctx @ Ws1^T + bs1) -> H1 (overwrite own ctx slice)
    gemm64(H1, Ws1, bs1, c);
    #pragma unroll
    for (int m = 0; m < 4; m++)
        #pragma unroll
        for (int n = 0; n < 4; n++)
            #pragma unroll
            for (int r = 0; r < 4; r++) c[m][n][r] = gelu_exact(c[m][n][r]);
    storeH(H1, c);

    // gates = sigmoid(hg @ Wg2^T + bg2); keep g0 broadcast
    float g0[4][4];
    {
        f32x4 c3[4];
        const float bv = (lr < 4) ? bg2[lr] : 0.f;
        #pragma unroll
        for (int m = 0; m < 4; m++){ f32x4 t = {bv,bv,bv,bv}; c3[m] = t; }
        #pragma unroll
        for (int kk = 0; kk < 2; kk++){
            short8 a[4];
            #pragma unroll
            for (int m = 0; m < 4; m++) a[m] = afrag(H2, m*16 + lr, kk*4 + lg);
            short8 w = {0,0,0,0,0,0,0,0};
            if (lr < 4) w = wfrag(Wg2, lr, kk*32 + lg*8);
            #pragma unroll
            for (int m = 0; m < 4; m++)
                c3[m] = __builtin_amdgcn_mfma_f32_16x16x32_bf16(a[m], w, c3[m], 0,0,0);
        }
        #pragma unroll
        for (int m = 0; m < 4; m++)
            #pragma unroll
            for (int r = 0; r < 4; r++){
                const float v = sigmoidf_(c3[m][r]);
                if (lr < 4)
                    gates[(size_t)(tokbase + wtok + m*16 + lg*4 + r)*4 + lr] = v;
                g0[m][r] = __shfl(v, lane & 48, 64);
            }
    }

    // scale = sigmoid(hs @ Ws2^T + bs2) -> repack via H1 -> coalesced store
    gemm64(H1, Ws2, bs2, c);
    #pragma unroll
    for (int m = 0; m < 4; m++)
        #pragma unroll
        for (int n = 0; n < 4; n++)
            #pragma unroll
            for (int r = 0; r < 4; r++) c[m][n][r] = sigmoidf_(c[m][n][r]);
    storeH(H1, c);
    {
        const size_t gtok = (size_t)tokbase + wtok + lane;
        #pragma unroll
        for (int fb = 0; fb < 8; fb++){
            const short8 v = *(const short8*)&H1[wv*4096 + lane*64 + ((fb ^ (lane & 7)) << 3)];
            *(short8*)&scaleb[gtok*64 + fb*8] = v;
        }
    }

    __syncthreads();                       // all waves done with H2 (hg)
    stage_coop(H2, x + (size_t)tokbase*64);
    __syncthreads();

    // self = x @ Wself^T + bself; acc = g0 * self
    gemm64(H2, Wself, bself, c);
    #pragma unroll
    for (int m = 0; m < 4; m++)
        #pragma unroll
        for (int n = 0; n < 4; n++)
            #pragma unroll
            for (int r = 0; r < 4; r++)
                acc[(size_t)(tokbase + wtok + m*16 + lg*4 + r)*64 + n*16 + lr]
                    = g0[m][r] * c[m][n][r];

    // fused transpose: xTp/xTd/xTs[bt][f][n0+t] from H2 (x bf16) + gates
    {
        const int f = tid >> 2, seg = tid & 3;
        const size_t ob = (size_t)bt*65536 + (size_t)f*1024 + n0 + seg*64;
        for (int i0 = 0; i0 < 64; i0 += 4){
            ushort4 vp, vd, vs;
            #pragma unroll
            for (int j = 0; j < 4; j++){
                const int t = seg*64 + i0 + j;
                const u16 raw = H2[t*64 + ((((f>>3) ^ (t & 7)) << 3) | (f & 7))];
                const float v = b2f(raw);
                (&vp.x)[j] = raw;
                (&vd.x)[j] = f2bf(v * dgate[t]);
                (&vs.x)[j] = f2bf(v * sgate[t]);
            }
            *(ushort4*)&xTp[ob + i0] = vp;
            *(ushort4*)&xTd[ob + i0] = vd;
            *(ushort4*)&xTs[ob + i0] = vs;
        }
    }
}

// ---------------------------------------------------------------------------
// MFMA diffusion GEMM + fused linear/gate epilogue (unchanged from r2).
// ---------------------------------------------------------------------------
template<bool WRITE_TMP>
__global__ __launch_bounds__(256, 2) void k_diffmm(
    const u16* __restrict__ adj,  const u16* __restrict__ srcT,
    const float* __restrict__ W,  const float* __restrict__ bias,
    const float* __restrict__ gates, const int branch,
    float* __restrict__ acc, u16* __restrict__ tmpT)
{
    __shared__ u16 sA[2][256*64];
    __shared__ u16 sB[2][64*64];

    const int tid = threadIdx.x;
    const int bt  = blockIdx.y;
    const int n0  = blockIdx.x * 256;
    const int wv  = tid >> 6, lane = tid & 63;
    const int lr  = lane & 15, lg = lane >> 4;
    const int wrow0 = wv * 64;

    const u16* asrc = adj  + (size_t)n0 * 1024;
    const u16* bsrc = srcT + (size_t)bt * 65536;

    auto stage = [&](int buf, int kt){
        const int m0 = kt * 64;
        #pragma unroll
        for (int i = 0; i < 8; i++){
            const int s = i*256 + tid;
            const int row = s >> 3, kbp = s & 7;
            const int kb = kbp ^ (row & 7);
            GLLDS(asrc + (size_t)row*1024 + m0 + kb*8, &sA[buf][s*8]);
        }
        #pragma unroll
        for (int i = 0; i < 2; i++){
            const int s = i*256 + tid;
            const int row = s >> 3, kbp = s & 7;
            const int kb = kbp ^ (row & 7);
            GLLDS(bsrc + (size_t)row*1024 + m0 + kb*8, &sB[buf][s*8]);
        }
    };

    const f32x4 z4 = {0.f, 0.f, 0.f, 0.f};
    f32x4 c[4][4];
    #pragma unroll
    for (int m = 0; m < 4; m++)
        #pragma unroll
        for (int n = 0; n < 4; n++) c[m][n] = z4;

    stage(0, 0);
    asm volatile("s_waitcnt vmcnt(0)" ::: "memory");
    __syncthreads();

    int cur = 0;
    for (int kt = 0; kt < 16; kt++){
        if (kt < 15) stage(cur ^ 1, kt + 1);
        const u16* A = sA[cur];
        const u16* B = sB[cur];
        short8 af[2][4], bfr[2][4];
        #pragma unroll
        for (int kk = 0; kk < 2; kk++){
            const int kb = lg + kk*4;
            #pragma unroll
            for (int m = 0; m < 4; m++){
                const int row = wrow0 + m*16 + lr;
                af[kk][m] = *(const short8*)&A[row*64 + ((kb ^ (row & 7)) << 3)];
            }
            #pragma unroll
            for (int n = 0; n < 4; n++){
                const int fr = n*16 + lr;
                bfr[kk][n] = *(const short8*)&B[fr*64 + ((kb ^ (fr & 7)) << 3)];
            }
        }
        #pragma unroll
        for (int kk = 0; kk < 2; kk++)
            #pragma unroll
            for (int m = 0; m < 4; m++)
                #pragma unroll
                for (int n = 0; n < 4; n++)
                    c[m][n] = __builtin_amdgcn_mfma_f32_16x16x32_bf16(
                        af[kk][m], bfr[kk][n], c[m][n], 0, 0, 0);
        asm volatile("s_waitcnt vmcnt(0)" ::: "memory");
        __syncthreads();
        cur ^= 1;
    }

    if (WRITE_TMP){
        #pragma unroll
        for (int m = 0; m < 4; m++)
            #pragma unroll
            for (int n = 0; n < 4; n++){
                const int f    = n*16 + lr;
                const int node = n0 + wrow0 + m*16 + lg*4;
                ushort4 v;
                v.x = f2bf(c[m][n][0]); v.y = f2bf(c[m][n][1]);
                v.z = f2bf(c[m][n][2]); v.w = f2bf(c[m][n][3]);
                *(ushort4*)&tmpT[(size_t)bt*65536 + (size_t)f*1024 + node] = v;
            }
    }

    u16* yT = &sA[0][0];
    u16* sW = &sB[0][0];
    #pragma unroll
    for (int m = 0; m < 4; m++)
        #pragma unroll
        for (int n = 0; n < 4; n++){
            const int f = n*16 + lr;
            #pragma unroll
            for (int r = 0; r < 4; r++){
                const int row = wrow0 + m*16 + lg*4 + r;
                yT[row*64 + (((f >> 3) ^ (row & 7)) << 3) + (f & 7)] = f2bf(c[m][n][r]);
            }
        }
    for (int i = tid; i < 4096; i += 256){
        const int o = i >> 6, f = i & 63;
        sW[o*64 + (((f >> 3) ^ (o & 7)) << 3) + (f & 7)] = f2bf(W[i]);
    }
    __syncthreads();

    f32x4 lin[4][4];
    #pragma unroll
    for (int m = 0; m < 4; m++)
        #pragma unroll
        for (int n = 0; n < 4; n++) lin[m][n] = z4;
    #pragma unroll
    for (int kk = 0; kk < 2; kk++){
        const int kb = lg + kk*4;
        short8 ya[4], wb[4];
        #pragma unroll
        for (int m = 0; m < 4; m++){
            const int row = wrow0 + m*16 + lr;
            ya[m] = *(const short8*)&yT[row*64 + ((kb ^ (row & 7)) << 3)];
        }
        #pragma unroll
        for (int n = 0; n < 4; n++){
            const int o = n*16 + lr;
            wb[n] = *(const short8*)&sW[o*64 + ((kb ^ (o & 7)) << 3)];
        }
        #pragma unroll
        for (int m = 0; m < 4; m++)
            #pragma unroll
            for (int n = 0; n < 4; n++)
                lin[m][n] = __builtin_amdgcn_mfma_f32_16x16x32_bf16(
                    ya[m], wb[n], lin[m][n], 0, 0, 0);
    }

    #pragma unroll
    for (int m = 0; m < 4; m++){
        float g[4];
        #pragma unroll
        for (int r = 0; r < 4; r++){
            const int node = n0 + wrow0 + m*16 + lg*4 + r;
            g[r] = gates[((size_t)bt*1024 + node)*4 + branch];
        }
        #pragma unroll
        for (int n = 0; n < 4; n++){
            const int f  = n*16 + lr;
            const float bv = bias[f];
            #pragma unroll
            for (int r = 0; r < 4; r++){
                const int node = n0 + wrow0 + m*16 + lg*4 + r;
                float* p = &acc[((size_t)bt*1024 + node)*64 + f];
                *p += g[r] * (lin[m][n][r] + bv);
            }
        }
    }
}

// ---------------------------------------------------------------------------
// Finalize: mixed = acc*scale; h = x + gelu(mixed); layernorm
// ---------------------------------------------------------------------------
__global__ __launch_bounds__(256) void k_final(
    const float* __restrict__ x, const u16* __restrict__ scaleb,
    const float* __restrict__ gamma, const float* __restrict__ beta,
    float* __restrict__ out)
{
    const int tid = threadIdx.x;
    const int w = tid >> 6, lane = tid & 63;
    const size_t tok  = (size_t)blockIdx.x*4 + w;
    const size_t base = tok*64 + lane;
    const float mixed = out[base] * b2f(scaleb[base]);
    const float h = x[base] + gelu_exact(mixed);
    float mu = h;
    #pragma unroll
    for (int o = 32; o > 0; o >>= 1) mu += __shfl_xor(mu, o, 64);
    mu *= (1.0f/64.0f);
    const float d = h - mu;
    float v = d*d;
    #pragma unroll
    for (int o = 32; o > 0; o >>= 1) v += __shfl_xor(v, o, 64);
    v *= (1.0f/64.0f);
    out[base] = d * rsqrtf(v + LN_EPS) * gamma[lane] + beta[lane];
}

// ---------------------------------------------------------------------------
extern "C" void kernel_launch(void* const* d_in, const int* in_sizes, int n_in,
                              void* d_out, int out_size, void* d_ws, size_t ws_size,
                              hipStream_t stream)
{
    const float* x      = (const float*)d_in[0];
    const float* a_fwd  = (const float*)d_in[1];
    const float* ctx    = (const float*)d_in[2];
    const float* W_self = (const float*)d_in[3];
    const float* b_self = (const float*)d_in[4];
    const float* W_fwd  = (const float*)d_in[5];
    const float* b_fwd  = (const float*)d_in[6];
    const float* W_bwd  = (const float*)d_in[7];
    const float* b_bwd  = (const float*)d_in[8];
    const float* W_adp  = (const float*)d_in[9];
    const float* b_adp  = (const float*)d_in[10];
    const float* Wg1    = (const float*)d_in[11];
    const float* bg1    = (const float*)d_in[12];
    const float* Wg2    = (const float*)d_in[13];
    const float* bg2    = (const float*)d_in[14];
    const float* Ws1    = (const float*)d_in[15];
    const float* bs1    = (const float*)d_in[16];
    const float* Ws2    = (const float*)d_in[17];
    const float* bs2    = (const float*)d_in[18];
    const float* W_src  = (const float*)d_in[19];
    const float* b_src  = (const float*)d_in[20];
    const float* W_dst  = (const float*)d_in[21];
    const float* b_dst  = (const float*)d_in[22];
    const float* emb_src= (const float*)d_in[23];
    const float* emb_dst= (const float*)d_in[24];
    const float* gamma  = (const float*)d_in[25];
    const float* beta   = (const float*)d_in[26];

    float* out = (float*)d_out;
    char*  w   = (char*)d_ws;
    const size_t MB48 = 50331648ull;
    u16* afwd_bf = (u16*)(w);
    u16* abwd_bf = (u16*)(w + 2097152ull);
    u16* aadp_bf = (u16*)(w + 4194304ull);
    u16* xTp     = (u16*)(w + 6291456ull);
    u16* xTd     = (u16*)(w + 6291456ull + 1*MB48);
    u16* xTs     = (u16*)(w + 6291456ull + 2*MB48);
    u16* tmpT    = (u16*)(w + 6291456ull + 3*MB48);
    u16* scaleb  = (u16*)(w + 6291456ull + 4*MB48);
    float* gates = (float*)(w + 6291456ull + 5*MB48);

    k_adp   <<<1024, 256, 0, stream>>>(emb_src, emb_dst, aadp_bf);
    k_cvt   <<<1024, 256, 0, stream>>>(a_fwd, afwd_bf);
    k_bwd   <<<dim3(32,32), 256, 0, stream>>>(a_fwd, abwd_bf);
    k_gating<<<1536, 256, 0, stream>>>(x, ctx, Wg1,bg1, Wg2,bg2, Ws1,bs1, Ws2,bs2,
                                       W_src,b_src, W_dst,b_dst, W_self,b_self,
                                       gates, scaleb, out, xTp, xTd, xTs);

    dim3 g(4, 384);
    k_diffmm<true ><<<g,256,0,stream>>>(afwd_bf, xTd,  W_fwd,      b_fwd,    gates, 1, out, tmpT);
    k_diffmm<false><<<g,256,0,stream>>>(afwd_bf, tmpT, W_fwd+4096, b_fwd+64, gates, 1, out, tmpT);
    k_diffmm<true ><<<g,256,0,stream>>>(abwd_bf, xTs,  W_bwd,      b_bwd,    gates, 2, out, tmpT);
    k_diffmm<false><<<g,256,0,stream>>>(abwd_bf, tmpT, W_bwd+4096, b_bwd+64, gates, 2, out, tmpT);
    k_diffmm<true ><<<g,256,0,stream>>>(aadp_bf, xTp,  W_adp,      b_adp,    gates, 3, out, tmpT);
    k_diffmm<false><<<g,256,0,stream>>>(aadp_bf, tmpT, W_adp+4096, b_adp+64, gates, 3, out, tmpT);

    k_final <<<98304, 256, 0, stream>>>(x, scaleb, gamma, beta, out);
}